// Round 5
// baseline (259.353 us; speedup 1.0000x reference)
//
#include <hip/hip_runtime.h>

// RotaryEmbedding2D: out[b,s] is a 64x64 block-diagonal rotation matrix.
// B=16, S=1024, D=64, q=16, h=32. BASE=10000, SCALE=1.
// For half-index h in [0,32): angle = (h<16 ? x : y) * 10000^{-(h%16)/16}
// Row 2h:   col 2h = cos, col 2h+1 = -sin
// Row 2h+1: col 2h = sin, col 2h+1 =  cos
//
// Strategy: hipMemsetAsync zeroes the whole 268 MB output on the same
// optimized fill path the harness's poison uses (~6.5 TB/s measured),
// then a small kernel writes only the 64 MiB of 64B lines that contain
// nonzeros, as FULL-LINE coalesced stores (4 consecutive lanes cover one
// line -> 16 full lines per wave-store, no partial-line RMW).

#define NBS 16384        // B*S
#define MPB 8            // matrices per block
#define NBLK (NBS / MPB) // 2048 blocks

typedef float vfloat4 __attribute__((ext_vector_type(4)));

__global__ __launch_bounds__(256) void rope2d_scatter_kernel(
    const float* __restrict__ spa,   // (B,S,2)
    float* __restrict__ out)         // (B,S,64,64), already zeroed
{
    const int t   = threadIdx.x;          // 0..255
    const int bs0 = blockIdx.x * MPB;     // first matrix of this block

    __shared__ float ssin[MPB * 32];
    __shared__ float scos[MPB * 32];

    // One sincos per thread: matrix m = t>>5, half-index h = t&31.
    {
        const int m = t >> 5;
        const int h = t & 31;
        const float xy   = spa[(bs0 + m) * 2 + (h >> 4)];  // h<16 -> x, else y
        const int   i    = h & 15;
        const float invf = exp2f(-(float)i * 0.83048202372184059f); // 10000^(-i/16)
        float s, c;
        sincosf(xy * invf, &s, &c);
        ssin[t] = s;
        scos[t] = c;
    }
    __syncthreads();

    // Each row r of each matrix has its nonzeros in ONE 64B line: the line
    // holding float4-group r>>2, i.e. quarter (r>>4) of the row. Write that
    // full line: 4 lanes per row, lane j writes group 4*(r>>4)+j; the value
    // group is j == (r>>2)&3, others are zero (line is fully overwritten,
    // so no dependence on the memset for these 16B groups).
    //
    // idx = t + 256*j over [0,2048): m = idx>>8, r = (idx>>2)&63, lj = idx&3.
    // Consecutive lanes -> consecutive 16B groups -> full 64B lines.
    vfloat4* outv = (vfloat4*)out + (size_t)bs0 * 1024;

    #pragma unroll
    for (int j = 0; j < MPB; ++j) {
        const int idx = t + j * 256;
        const int m   = idx >> 8;
        const int r   = (idx >> 2) & 63;
        const int lj  = idx & 3;
        vfloat4 v = (vfloat4)(0.f, 0.f, 0.f, 0.f);
        if (lj == ((r >> 2) & 3)) {
            const float s = ssin[m * 32 + (r >> 1)];
            const float c = scos[m * 32 + (r >> 1)];
            const float e0 = (r & 1) ? s : c;   // odd row: sin,cos ; even: cos,-sin
            const float e1 = (r & 1) ? c : -s;
            if (r & 2) { v.z = e0; v.w = e1; }
            else       { v.x = e0; v.y = e1; }
        }
        // float4 index: m*1024 + r*16 + (r>>4)*4 + lj
        outv[m * 1024 + r * 16 + (r >> 4) * 4 + lj] = v;
    }
}

extern "C" void kernel_launch(void* const* d_in, const int* in_sizes, int n_in,
                              void* d_out, int out_size, void* d_ws, size_t ws_size,
                              hipStream_t stream) {
    const float* spa = (const float*)d_in[0];
    float* out = (float*)d_out;
    // Bulk zeros via the driver's optimized fill path (graph memset node).
    hipMemsetAsync(out, 0, (size_t)out_size * sizeof(float), stream);
    // Then overwrite the 1M nonzero 64B lines (stream-ordered after memset).
    rope2d_scatter_kernel<<<NBLK, 256, 0, stream>>>(spa, out);
}